// Round 1
// baseline (12592.308 us; speedup 1.0000x reference)
//
#include <hip/hip_runtime.h>
#include <cstdint>
#include <cstddef>

#define V_SZ 32000
#define H_SZ 1024
#define T_SZ 512
#define B_SZ 64

typedef short short8 __attribute__((ext_vector_type(8)));
typedef float f32x4 __attribute__((ext_vector_type(4)));

__device__ __forceinline__ short f2bf(float f) {
  union { float f; unsigned u; } v; v.f = f;
  unsigned r = (v.u + 0x7fffu + ((v.u >> 16) & 1u)) >> 16;  // RNE, inputs finite
  return (short)r;
}

// embT[v][h] = bf16(emb_w[h][v] + emb_b[h])  -- tiled transpose, both sides coalesced
__global__ __launch_bounds__(256) void k_embT(const float* __restrict__ emb_w,
                                              const float* __restrict__ emb_b,
                                              short* __restrict__ embT) {
  __shared__ float tile[64][65];  // +1 pad: column reads conflict-free
  const int v0 = blockIdx.x * 64, h0 = blockIdx.y * 64;
  const int c = threadIdx.x & 63, rg = threadIdx.x >> 6;
#pragma unroll
  for (int p = 0; p < 16; ++p) {
    int r = rg * 16 + p;
    tile[r][c] = emb_w[(size_t)(h0 + r) * V_SZ + v0 + c];
  }
  __syncthreads();
  const float bias = emb_b[h0 + c];
#pragma unroll
  for (int p = 0; p < 16; ++p) {
    int vr = rg * 16 + p;
    embT[(size_t)(v0 + vr) * H_SZ + h0 + c] = f2bf(tile[c][vr] + bias);
  }
}

__global__ __launch_bounds__(256) void k_cast(const float* __restrict__ s,
                                              short* __restrict__ d, int n) {
  for (int i = blockIdx.x * 256 + threadIdx.x; i < n; i += gridDim.x * 256)
    d[i] = f2bf(s[i]);
}

__global__ __launch_bounds__(256) void k_copy(const float* __restrict__ s,
                                              float* __restrict__ d, int n) {
  for (int i = blockIdx.x * 256 + threadIdx.x; i < n; i += gridDim.x * 256)
    d[i] = s[i];
}

// One LSTM time-step, both directions. grid = 128 blocks:
//   d = blockIdx.x>>6 (0=fwd,1=bwd), n0 = (blockIdx.x&63)*16 output columns.
// Block = 4 waves; wave w owns gate w (i,o,f,g) for all 64 batch rows x 16 cols.
// K = 2048 (x-part 0..1023 from embT[token], h-part 1024..2047 from hbf phase buf).
__global__ __launch_bounds__(256) void k_step(int t,
    const int* __restrict__ tokens, const short* __restrict__ embT,
    const short* __restrict__ Wbf, const float* __restrict__ biasws,
    short* __restrict__ hbf, float* __restrict__ cst, float* __restrict__ out) {
  // per buffer: A tile [64 rows][64 k] bf16 @ byte 0, B tile [64 rows=(g,n)][64 k] @ byte 8192
  __shared__ __align__(16) short smem[2][8192];
  __shared__ float Pb[4096];  // [4 gates][64 b][16 n] f32 preactivations

  const int tid = threadIdx.x;
  const int d = blockIdx.x >> 6;
  const int n0 = (blockIdx.x & 63) << 4;
  const int lane = tid & 63, w = tid >> 6;
  const int l15 = lane & 15, l4 = lane >> 4;
  const int swz = (lane & 7) << 4;  // XOR swizzle: rows spread across 8 bank groups
  const int t_dir = d ? (T_SZ - 1 - t) : t;

  const short* hsrc = hbf + (size_t)(t & 1) * 131072 + (size_t)d * 65536;
  short*       hdst = hbf + (size_t)((t + 1) & 1) * 131072 + (size_t)d * 65536;

  // ---- staging thread-constants (each thread owns 2 A-chunks + 2 B-chunks of 16B) ----
  int arow[2], acol[2], aoff[2], boff[2], tokv[2];
  const short* srcB[2];
#pragma unroll
  for (int p = 0; p < 2; ++p) {
    int cid = tid + p * 256;             // 0..511
    arow[p] = cid >> 3;                  // batch row 0..63
    acol[p] = (cid & 7) * 8;             // k offset within 64-chunk
    aoff[p] = ((arow[p] * 64 + acol[p]) * 2) ^ ((arow[p] & 7) << 4);
    tokv[p] = tokens[t_dir * B_SZ + arow[p]];
    int q = cid >> 3;                    // (gate,n) row 0..63
    int bg = q >> 4, bn = q & 15, bcol = (cid & 7) * 8;
    boff[p] = (8192 + (q * 64 + bcol) * 2) ^ ((q & 7) << 4);
    srcB[p] = Wbf + (size_t)((d * 4 + bg) * 1024 + n0 + bn) * 2048 + bcol;
  }

  // ---- compute-side fragment byte offsets ----
  int rbA[4];
#pragma unroll
  for (int mt = 0; mt < 4; ++mt) rbA[mt] = (mt * 16 + l15) * 128 + l4 * 16;
  const int rbB = 8192 + (w * 16 + l15) * 128 + l4 * 16;

  f32x4 acc[4] = {{0,0,0,0},{0,0,0,0},{0,0,0,0},{0,0,0,0}};

  auto LOADC = [&](int c, short8* a2, short8* b2) {
    int k0 = c * 64;
#pragma unroll
    for (int p = 0; p < 2; ++p) {
      const short* s = (k0 < 1024)
          ? embT + (size_t)tokv[p] * 1024 + k0 + acol[p]
          : hsrc + arow[p] * 1024 + (k0 - 1024) + acol[p];
      a2[p] = *(const short8*)s;
      b2[p] = *(const short8*)(srcB[p] + k0);
    }
  };
  auto STOREC = [&](int c, const short8* a2, const short8* b2) {
    char* base = (char*)smem[c & 1];
#pragma unroll
    for (int p = 0; p < 2; ++p) {
      *(short8*)(base + aoff[p]) = a2[p];
      *(short8*)(base + boff[p]) = b2[p];
    }
  };

  {
    short8 av[2], bv[2];
    LOADC(0, av, bv);
    STOREC(0, av, bv);
  }
  __syncthreads();

  for (int c = 0; c < 32; ++c) {
    short8 nav[2], nbv[2];
    if (c < 31) LOADC(c + 1, nav, nbv);  // issue-early: HBM/L2 latency hides under MFMA
    char* base = (char*)smem[c & 1];
#pragma unroll
    for (int kk = 0; kk < 2; ++kk) {
      short8 bfr = *(const short8*)(base + ((rbB + kk * 64) ^ swz));
#pragma unroll
      for (int mt = 0; mt < 4; ++mt) {
        short8 afr = *(const short8*)(base + ((rbA[mt] + kk * 64) ^ swz));
        acc[mt] = __builtin_amdgcn_mfma_f32_16x16x32_bf16(afr, bfr, acc[mt], 0, 0, 0);
      }
    }
    if (c < 31) STOREC(c + 1, nav, nbv);  // write-late into the other buffer
    __syncthreads();
  }

  // ---- publish gate preactivations (C layout: row=(lane>>4)*4+i, col=lane&15) ----
#pragma unroll
  for (int mt = 0; mt < 4; ++mt)
#pragma unroll
    for (int i = 0; i < 4; ++i) {
      int b = mt * 16 + l4 * 4 + i;
      Pb[w * 1024 + b * 16 + l15] = acc[mt][i];
    }
  __syncthreads();

  // ---- gate math + state update + output write ----
  const float* bias = biasws + d * 4096;
  float* cstd = cst + (size_t)d * 65536;
#pragma unroll
  for (int p = 0; p < 4; ++p) {
    int id = tid + p * 256;              // = b*16 + nn
    int b = id >> 4, nn = id & 15, col = n0 + nn;
    float pi = Pb[id]        + bias[col];
    float po = Pb[1024 + id] + bias[1024 + col];
    float pf = Pb[2048 + id] + bias[2048 + col];
    float pg = Pb[3072 + id] + bias[3072 + col];
    float ig = 1.0f / (1.0f + expf(-pi));
    float og = 1.0f / (1.0f + expf(-po));
    float fg = 1.0f / (1.0f + expf(-pf));
    float cg = tanhf(pg);
    int sidx = b * 1024 + col;
    float cold = cstd[sidx];
    float cnew = fg * cold + ig * cg;
    float hnew = og * tanhf(cnew);
    cstd[sidx] = cnew;
    hdst[sidx] = f2bf(hnew);
    size_t o = (size_t)(t * 64 + b) * 2048 + d * 1024 + col;
    out[o] = hnew;                 // hidden_states
    out[o + 67108864] = cnew;      // cell_states (offset T*B*2H)
  }
}

extern "C" void kernel_launch(void* const* d_in, const int* in_sizes, int n_in,
                              void* d_out, int out_size, void* d_ws, size_t ws_size,
                              hipStream_t stream) {
  (void)in_sizes; (void)n_in; (void)out_size; (void)ws_size;
  const int* tokens  = (const int*)d_in[0];
  const float* emb_w = (const float*)d_in[1];
  const float* emb_b = (const float*)d_in[2];

  char* ws = (char*)d_ws;
  // ws layout (bytes):
  short* embT   = (short*)(ws);               // 32000*1024*2      = 65,536,000
  short* Wbf    = (short*)(ws + 65536000);    // 8*1024*2048*2     = 33,554,432
  float* biasws = (float*)(ws + 99090432);    // 8*1024*4          =     32,768
  short* hbf    = (short*)(ws + 99123200);    // 2 phase * 2*64*1024*2 = 524,288
  float* cst    = (float*)(ws + 99647488);    // 2*64*1024*4       =    524,288
  // total 100,171,776 B

  // zero h (both phase buffers) and c each call (deterministic)
  hipMemsetAsync(ws + 99123200, 0, 524288 + 524288, stream);

  k_embT<<<dim3(500, 16), 256, 0, stream>>>(emb_w, emb_b, embT);

  for (int d = 0; d < 2; ++d)
    for (int g = 0; g < 4; ++g) {
      const float* wsrc = (const float*)d_in[3 + d * 8 + g * 2];
      const float* bsrc = (const float*)d_in[4 + d * 8 + g * 2];
      k_cast<<<1024, 256, 0, stream>>>(wsrc, Wbf + (size_t)(d * 4 + g) * 1024 * 2048,
                                       1024 * 2048);
      k_copy<<<4, 256, 0, stream>>>(bsrc, biasws + (d * 4 + g) * 1024, 1024);
    }

  for (int t = 0; t < T_SZ; ++t)
    k_step<<<128, 256, 0, stream>>>(t, tokens, embT, Wbf, biasws, hbf, cst,
                                    (float*)d_out);
}